// Round 10
// baseline (633.420 us; speedup 1.0000x reference)
//
#include <hip/hip_runtime.h>

#define HDIM 64

__device__ __forceinline__ float fast_sigmoid(float v) {
    return __builtin_amdgcn_rcpf(1.0f + __builtin_amdgcn_exp2f(-1.442695041f * v));
}

__device__ __forceinline__ float fast_tanh(float v) {
    return 1.0f - 2.0f * __builtin_amdgcn_rcpf(1.0f + __builtin_amdgcn_exp2f(2.885390082f * v));
}

// 128 threads = 2 waves per batch element (512 blocks).
// wave 0: lane l owns gate rows {l, 64+l}      (i, f) of unit l — full K=64 dots
// wave 1: lane l owns gate rows {128+l, 192+l} (g, o) of unit l
// 128 recurrent weights per lane, pinned in VGPRs.
// NO cross-lane reduction (dot is lane-local). ONE barrier per step (activated
// gate-pair exchange via LDS, parity double-buffered). h is kept in TWO
// PRIVATE LDS copies: each wave writes its own copy and re-reads it next step
// — safe by the wave's in-order DS pipe (correctness validated in round 7),
// so the h hand-off needs no barrier.
// x staged through LDS per 64-step chunk (avoids per-step vmcnt drain at the
// barrier). T assumed even (T=1000), chunk lengths 64/40 both even.
__global__ __launch_bounds__(128)
__attribute__((amdgpu_waves_per_eu(2, 2)))
void bilstm_kernel(const float* __restrict__ x,
                   const float* __restrict__ w_ih_f,
                   const float* __restrict__ w_hh_f,
                   const float* __restrict__ b_ih_f,
                   const float* __restrict__ b_hh_f,
                   const float* __restrict__ w_ih_b,
                   const float* __restrict__ b_ih_b,
                   const float* __restrict__ b_hh_b,
                   const float* __restrict__ w_fc,
                   const float* __restrict__ b_fc,
                   float* __restrict__ out,
                   int T)
{
    const int b   = blockIdx.x;
    const int tid = threadIdx.x;
    const int w   = tid >> 6;        // 0: gates {i,f}, 1: gates {g,o}
    const int l   = tid & 63;        // unit index

    __shared__ __align__(16) float hbuf[2][HDIM];     // per-wave PRIVATE h copy
    __shared__ __align__(16) float gbuf[2][2][2*HDIM];// [parity][wave][2*l]
    __shared__ __align__(16) float xstage[2][256];    // 64 steps x 4 comps

    // ---- per-lane weights: 2 full gate rows (r0 = w*128+l, r1 = r0+64) ----
    const int r0 = (w << 7) | l;
    const int r1 = r0 + 64;

    float4 wv0[16], wv1[16];
    {
        const float* row0 = w_hh_f + (size_t)r0 * HDIM;
        const float* row1 = w_hh_f + (size_t)r1 * HDIM;
        #pragma unroll
        for (int q = 0; q < 16; ++q) {
            wv0[q] = ((const float4*)row0)[q];
            wv1[q] = ((const float4*)row1)[q];
        }
    }
    // Pin: forbid rematerialization of weight loads inside the t-loop.
    #pragma unroll
    for (int q = 0; q < 16; q += 2) {
        asm volatile("" : "+v"(wv0[q].x), "+v"(wv0[q].y), "+v"(wv0[q].z), "+v"(wv0[q].w),
                          "+v"(wv0[q+1].x), "+v"(wv0[q+1].y), "+v"(wv0[q+1].z), "+v"(wv0[q+1].w));
        asm volatile("" : "+v"(wv1[q].x), "+v"(wv1[q].y), "+v"(wv1[q].z), "+v"(wv1[q].w),
                          "+v"(wv1[q+1].x), "+v"(wv1[q+1].y), "+v"(wv1[q+1].z), "+v"(wv1[q+1].w));
    }

    float4 wx0 = *(const float4*)(w_ih_f + (size_t)r0 * 4);
    float4 wx1 = *(const float4*)(w_ih_f + (size_t)r1 * 4);
    float  bz0 = b_ih_f[r0] + b_hh_f[r0];
    float  bz1 = b_ih_f[r1] + b_hh_f[r1];
    asm volatile("" : "+v"(wx0.x), "+v"(wx0.y), "+v"(wx0.z), "+v"(wx0.w), "+v"(bz0));
    asm volatile("" : "+v"(wx1.x), "+v"(wx1.y), "+v"(wx1.z), "+v"(wx1.w), "+v"(bz1));

    const float* xb = x + (size_t)b * T * 4;
    const int lim = T * 4 - 1;

    // prologue: stage chunk 0 (128 threads x 2 floats), init own h copy
    {
        int i0 = tid;        if (i0 > lim) i0 = lim;
        int i1 = tid + 128;  if (i1 > lim) i1 = lim;
        xstage[0][tid]       = xb[i0];
        xstage[0][tid + 128] = xb[i1];
    }
    hbuf[w][l] = 0.0f;   // own copy; in-order DS makes it visible to own reads
    __syncthreads();

    float c = 0.0f, h = 0.0f;
    const int NCH = (T + 63) >> 6;

    for (int ch = 0; ch < NCH; ++ch) {
        const int nst = ((T - (ch << 6)) < 64) ? (T - (ch << 6)) : 64;
        const float* xs = xstage[ch & 1];
        const bool more = (ch + 1 < NCH);
        float xn0 = 0.0f, xn1 = 0.0f;
        if (more) {
            int i0 = ((ch + 1) << 8) + tid;        if (i0 > lim) i0 = lim;
            int i1 = ((ch + 1) << 8) + tid + 128;  if (i1 > lim) i1 = lim;
            xn0 = xb[i0];
            xn1 = xb[i1];   // drained once per chunk at a barrier, not per step
        }

        #define STEP(S, P) do {                                              \
            const float4 xt = *(const float4*)(&xs[(S) << 2]);               \
            const float4* hp = (const float4*)hbuf[w];                       \
            /* 8 accumulator chains, 16 deep each */                         \
            float a00 = bz0, a01 = wx0.x * xt.x + wx0.y * xt.y;              \
            float a02 = wx0.z * xt.z + wx0.w * xt.w, a03 = 0.0f;             \
            float a10 = bz1, a11 = wx1.x * xt.x + wx1.y * xt.y;              \
            float a12 = wx1.z * xt.z + wx1.w * xt.w, a13 = 0.0f;             \
            _Pragma("unroll")                                                \
            for (int q = 0; q < 16; ++q) {                                   \
                const float4 hv = hp[q];   /* broadcast b128, own copy */    \
                a00 += wv0[q].x * hv.x; a01 += wv0[q].y * hv.y;              \
                a02 += wv0[q].z * hv.z; a03 += wv0[q].w * hv.w;              \
                a10 += wv1[q].x * hv.x; a11 += wv1[q].y * hv.y;              \
                a12 += wv1[q].z * hv.z; a13 += wv1[q].w * hv.w;              \
            }                                                                \
            const float A0 = (a00 + a01) + (a02 + a03);                      \
            const float A1 = (a10 + a11) + (a12 + a13);                      \
            float s0, s1;                                                    \
            if (w == 0) { s0 = fast_sigmoid(A0); s1 = fast_sigmoid(A1); }    \
            else        { s0 = fast_tanh(A0);    s1 = fast_sigmoid(A1); }    \
            *(float2*)(&gbuf[P][w][l << 1]) = make_float2(s0, s1);           \
            __syncthreads();                                                 \
            const float2 ov = *(const float2*)(&gbuf[P][w ^ 1][l << 1]);     \
            float gi, gf, gg, go;                                            \
            if (w == 0) { gi = s0; gf = s1; gg = ov.x; go = ov.y; }          \
            else        { gg = s0; go = s1; gi = ov.x; gf = ov.y; }          \
            c = gf * c + gi * gg;                                            \
            h = go * fast_tanh(c);                                           \
            hbuf[w][l] = h;             /* own copy; no barrier needed */    \
            asm volatile("" ::: "memory");                                   \
        } while (0)

        for (int s = 0; s < nst; s += 2) {
            STEP(s,     0);
            STEP(s + 1, 1);
        }
        #undef STEP

        if (more) {
            xstage[(ch + 1) & 1][tid]       = xn0;
            xstage[(ch + 1) & 1][tid + 128] = xn1;
            __syncthreads();
        }
    }

    // ---- epilogue: wave 0 only — backward cell + fc + sigmoid ----
    if (w == 0) {
        // backward-direction single cell from zero state at x[:, T-1]
        // (w_hh_b never multiplies nonzero state)
        float4 xl = *(const float4*)(xb + 4 * (T - 1));
        float gb[4];
        #pragma unroll
        for (int jj = 0; jj < 4; ++jj) {
            const int rr2 = (jj << 6) | l;
            float4 wb = *(const float4*)(w_ih_b + (size_t)rr2 * 4);
            gb[jj] = b_ih_b[rr2] + b_hh_b[rr2]
                   + wb.x * xl.x + wb.y * xl.y + wb.z * xl.z + wb.w * xl.w;
        }
        const float ib  = fast_sigmoid(gb[0]);
        const float ggv = fast_tanh(gb[2]);
        const float ob  = fast_sigmoid(gb[3]);
        const float cb  = ib * ggv;
        const float hbk = ob * fast_tanh(cb);

        // h register holds the final forward h for unit l
        float p = w_fc[l] * h + w_fc[HDIM + l] * hbk;
        #pragma unroll
        for (int off = 32; off; off >>= 1) p += __shfl_xor(p, off);

        if (l == 0) out[b] = fast_sigmoid(p + b_fc[0]);
    }
}

extern "C" void kernel_launch(void* const* d_in, const int* in_sizes, int n_in,
                              void* d_out, int out_size, void* d_ws, size_t ws_size,
                              hipStream_t stream) {
    const float* x      = (const float*)d_in[0];
    const float* w_ih_f = (const float*)d_in[1];
    const float* w_hh_f = (const float*)d_in[2];
    const float* b_ih_f = (const float*)d_in[3];
    const float* b_hh_f = (const float*)d_in[4];
    const float* w_ih_b = (const float*)d_in[5];
    // d_in[6] = w_hh_b — unused (backward cell starts from zero state)
    const float* b_ih_b = (const float*)d_in[7];
    const float* b_hh_b = (const float*)d_in[8];
    const float* w_fc   = (const float*)d_in[9];
    const float* b_fc   = (const float*)d_in[10];
    float* out = (float*)d_out;

    const int B = out_size;                 // 512
    const int T = in_sizes[0] / (B * 4);    // 1000

    bilstm_kernel<<<dim3(B), dim3(128), 0, stream>>>(
        x, w_ih_f, w_hh_f, b_ih_f, b_hh_f,
        w_ih_b, b_ih_b, b_hh_b, w_fc, b_fc, out, T);
}

// Round 11
// 509.574 us; speedup vs baseline: 1.2430x; 1.2430x over previous
//
#include <hip/hip_runtime.h>

#define HDIM 64

__device__ __forceinline__ float fast_sigmoid(float v) {
    return __builtin_amdgcn_rcpf(1.0f + __builtin_amdgcn_exp2f(-1.442695041f * v));
}

__device__ __forceinline__ float fast_tanh(float v) {
    return 1.0f - 2.0f * __builtin_amdgcn_rcpf(1.0f + __builtin_amdgcn_exp2f(2.885390082f * v));
}

// 256 threads = 4 waves per batch element (r6 structure, 503 us baseline).
// lane l of wave w:  j = l>>4 (k-slice group), i = l&15, output m = w*16+i.
// Lane holds 64 recurrent weights (4 gates x k-slice 16), pinned in VGPRs.
// Round-11 changes:
//  (1) anti-phase stagger: half the blocks s_sleep ~320cy once so the two
//      co-resident blocks/CU interleave their serial chains instead of
//      running phase-locked (observed step time == 2x single-chain latency).
//  (2) x staged TRANSPOSED [comp][step+pad]: one ds_read_b128 per 4 steps
//      into registers, x-term folded AFTER the h-FMA loop -> x never sits on
//      the front of the per-step dependency chain.
__global__ __launch_bounds__(256)
__attribute__((amdgpu_waves_per_eu(2, 2)))
void bilstm_kernel(const float* __restrict__ x,
                   const float* __restrict__ w_ih_f,
                   const float* __restrict__ w_hh_f,
                   const float* __restrict__ b_ih_f,
                   const float* __restrict__ b_hh_f,
                   const float* __restrict__ w_ih_b,
                   const float* __restrict__ b_ih_b,
                   const float* __restrict__ b_hh_b,
                   const float* __restrict__ w_fc,
                   const float* __restrict__ b_fc,
                   float* __restrict__ out,
                   int T)
{
    const int b   = blockIdx.x;
    const int tid = threadIdx.x;
    const int w   = tid >> 6;        // wave 0..3
    const int l   = tid & 63;        // lane 0..63
    const int j   = l >> 4;          // k-slice group 0..3
    const int i   = l & 15;
    const int m   = (w << 4) | i;    // output index 0..63

    __shared__ __align__(16) float hbuf[2][HDIM];
    __shared__ __align__(16) float xstage[2][4][68];   // [parity][comp][step] (+4 pad)

    // ---- per-lane weights: 4 gates x k-slice [16j,16j+16) ----
    float4 wv[4][4];
    float  wx[4], bz[4];
    #pragma unroll
    for (int g = 0; g < 4; ++g) {
        const int r = (g << 6) | m;
        const float* row = w_hh_f + (size_t)r * HDIM + (j << 4);
        #pragma unroll
        for (int q = 0; q < 4; ++q) wv[g][q] = ((const float4*)row)[q];
        wx[g] = w_ih_f[(size_t)r * 4 + j];                  // x-weight, component j
        bz[g] = (j == 0) ? (b_ih_f[r] + b_hh_f[r]) : 0.0f;  // bias seeded once
    }
    #pragma unroll
    for (int g = 0; g < 4; ++g) {
        #pragma unroll
        for (int q = 0; q < 4; ++q)
            asm volatile("" : "+v"(wv[g][q].x), "+v"(wv[g][q].y),
                              "+v"(wv[g][q].z), "+v"(wv[g][q].w));
    }
    asm volatile("" : "+v"(wx[0]), "+v"(wx[1]), "+v"(wx[2]), "+v"(wx[3]));
    asm volatile("" : "+v"(bz[0]), "+v"(bz[1]), "+v"(bz[2]), "+v"(bz[3]));

    const float* xb = x + (size_t)b * T * 4;
    const int lim = T * 4 - 1;

    // prologue: stage chunk 0 transposed, zero h
    {
        int idx = tid;  if (idx > lim) idx = lim;
        xstage[0][tid & 3][tid >> 2] = xb[idx];
    }
    if (tid < HDIM) hbuf[0][tid] = 0.0f;
    __syncthreads();

    // ---- anti-phase stagger: offset half the blocks by ~320 cycles ----
    if (((b & 1) ^ ((b >> 8) & 1)) != 0) __builtin_amdgcn_s_sleep(5);

    float c = 0.0f, h = 0.0f;
    const int NCH = (T + 63) >> 6;   // chunks of 64 timesteps

    for (int ch = 0; ch < NCH; ++ch) {
        const int nst = ((T - (ch << 6)) < 64) ? (T - (ch << 6)) : 64;
        const float (*xs)[68] = xstage[ch & 1];
        const bool more = (ch + 1 < NCH);
        float xnf = 0.0f;
        if (more) {
            int idx = ((ch + 1) << 8) + tid;  if (idx > lim) idx = lim;
            xnf = xb[idx];   // drained once per chunk, not per step
        }

        #define ACCP(HV, Q)                                               \
            p0 += wv[0][Q].x * HV.x; p0 += wv[0][Q].y * HV.y;             \
            p0 += wv[0][Q].z * HV.z; p0 += wv[0][Q].w * HV.w;             \
            p1 += wv[1][Q].x * HV.x; p1 += wv[1][Q].y * HV.y;             \
            p1 += wv[1][Q].z * HV.z; p1 += wv[1][Q].w * HV.w;             \
            p2 += wv[2][Q].x * HV.x; p2 += wv[2][Q].y * HV.y;             \
            p2 += wv[2][Q].z * HV.z; p2 += wv[2][Q].w * HV.w;             \
            p3 += wv[3][Q].x * HV.x; p3 += wv[3][Q].y * HV.y;             \
            p3 += wv[3][Q].z * HV.z; p3 += wv[3][Q].w * HV.w;
        #define ACCQ(HV, Q)                                               \
            q0 += wv[0][Q].x * HV.x; q0 += wv[0][Q].y * HV.y;             \
            q0 += wv[0][Q].z * HV.z; q0 += wv[0][Q].w * HV.w;             \
            q1 += wv[1][Q].x * HV.x; q1 += wv[1][Q].y * HV.y;             \
            q1 += wv[1][Q].z * HV.z; q1 += wv[1][Q].w * HV.w;             \
            q2 += wv[2][Q].x * HV.x; q2 += wv[2][Q].y * HV.y;             \
            q2 += wv[2][Q].z * HV.z; q2 += wv[2][Q].w * HV.w;             \
            q3 += wv[3][Q].x * HV.x; q3 += wv[3][Q].y * HV.y;             \
            q3 += wv[3][Q].z * HV.z; q3 += wv[3][Q].w * HV.w;

        // XJ arrives in a register (loaded once per 4 steps); folded AFTER the
        // h-FMA loop so it is never on the front of the dependency chain.
        #define STEP(XJ, RA, RB) do {                                      \
            const float4* hp = (const float4*)(&hbuf[RA][j << 4]);         \
            float4 h0 = hp[0], h1 = hp[1], h2 = hp[2], h3 = hp[3];         \
            float p0 = bz[0], p1 = bz[1], p2 = bz[2], p3 = bz[3];          \
            float q0 = 0.0f, q1 = 0.0f, q2 = 0.0f, q3 = 0.0f;              \
            ACCP(h0, 0) ACCQ(h1, 1) ACCP(h2, 2) ACCQ(h3, 3)                \
            q0 += wx[0] * (XJ); q1 += wx[1] * (XJ);                        \
            q2 += wx[2] * (XJ); q3 += wx[3] * (XJ);                        \
            p0 += q0; p1 += q1; p2 += q2; p3 += q3;                        \
            p0 += __shfl_xor(p0, 16); p1 += __shfl_xor(p1, 16);            \
            p2 += __shfl_xor(p2, 16); p3 += __shfl_xor(p3, 16);            \
            p0 += __shfl_xor(p0, 32); p1 += __shfl_xor(p1, 32);            \
            p2 += __shfl_xor(p2, 32); p3 += __shfl_xor(p3, 32);            \
            const float gi = fast_sigmoid(p0);                             \
            const float gf = fast_sigmoid(p1);                             \
            const float gg = fast_tanh(p2);                                \
            const float go = fast_sigmoid(p3);                             \
            c = gf * c + gi * gg;                                          \
            h = go * fast_tanh(c);                                         \
            if (l < 16) hbuf[RB][m] = h;                                   \
            __syncthreads();                                               \
        } while (0)

        for (int s = 0; s < nst; s += 4) {
            const float4 xq = *(const float4*)(&xs[j][s]);  // 1 b128 / 4 steps
            STEP(xq.x, 0, 1);
            STEP(xq.y, 1, 0);
            STEP(xq.z, 0, 1);
            STEP(xq.w, 1, 0);
        }
        #undef STEP
        #undef ACCP
        #undef ACCQ

        if (more) {
            xstage[(ch + 1) & 1][tid & 3][tid >> 2] = xnf;
            __syncthreads();
        }
    }

    // ---- epilogue: wave 0 handles backward cell + fc + sigmoid ----
    if (w == 0) {
        // backward-direction single cell from zero state at x[:, T-1]
        // (w_hh_b never multiplies nonzero state)
        float4 xl = *(const float4*)(xb + 4 * (T - 1));
        float gb[4];
        #pragma unroll
        for (int jj = 0; jj < 4; ++jj) {
            const int rr2 = (jj << 6) | l;
            float4 wb = *(const float4*)(w_ih_b + (size_t)rr2 * 4);
            gb[jj] = b_ih_b[rr2] + b_hh_b[rr2]
                   + wb.x * xl.x + wb.y * xl.y + wb.z * xl.z + wb.w * xl.w;
        }
        const float ib  = fast_sigmoid(gb[0]);
        const float ggv = fast_tanh(gb[2]);
        const float ob  = fast_sigmoid(gb[3]);
        const float cb  = ib * ggv;
        const float hbk = ob * fast_tanh(cb);

        const float hf = hbuf[0][l];   // T even -> final h lands in buffer 0
        float p = w_fc[l] * hf + w_fc[HDIM + l] * hbk;
        #pragma unroll
        for (int off = 32; off; off >>= 1) p += __shfl_xor(p, off);

        if (l == 0) out[b] = fast_sigmoid(p + b_fc[0]);
    }
}

extern "C" void kernel_launch(void* const* d_in, const int* in_sizes, int n_in,
                              void* d_out, int out_size, void* d_ws, size_t ws_size,
                              hipStream_t stream) {
    const float* x      = (const float*)d_in[0];
    const float* w_ih_f = (const float*)d_in[1];
    const float* w_hh_f = (const float*)d_in[2];
    const float* b_ih_f = (const float*)d_in[3];
    const float* b_hh_f = (const float*)d_in[4];
    const float* w_ih_b = (const float*)d_in[5];
    // d_in[6] = w_hh_b — unused (backward cell starts from zero state)
    const float* b_ih_b = (const float*)d_in[7];
    const float* b_hh_b = (const float*)d_in[8];
    const float* w_fc   = (const float*)d_in[9];
    const float* b_fc   = (const float*)d_in[10];
    float* out = (float*)d_out;

    const int B = out_size;                 // 512
    const int T = in_sizes[0] / (B * 4);    // 1000

    bilstm_kernel<<<dim3(B), dim3(256), 0, stream>>>(
        x, w_ih_f, w_hh_f, b_ih_f, b_hh_f,
        w_ih_b, b_ih_b, b_hh_b, w_fc, b_fc, out, T);
}